// Round 5
// baseline (110.713 us; speedup 1.0000x reference)
//
#include <hip/hip_runtime.h>
#include <hip/hip_bf16.h>

// FuzzyContrastiveLearning: loss = mean_i[ -log(pos_i / (all_i + eps)) ]
// Symmetric Gram, triangular 256^2 tiles (528), persistent balanced grid (512),
// m201-exact 8-phase K-schedule: 1 half-tile stage per phase, counted vmcnt(6),
// no clobbers on waitcnt asm, lgkmcnt(0)+sched_barrier before each MFMA quad,
// T2 XOR swizzle, T5 setprio, underflow-skip epilogue.

#define NROWS 8192
#define DIM   768
#define BM    256
#define BK    64
#define NKT   (DIM / BK)               // 12
#define NBLK  (NROWS / BM)             // 32
#define NTILES (NBLK * (NBLK + 1) / 2) // 528 (divisible by 8)
#define GRID  512
#define L2E   1.4426950408889634f

typedef __attribute__((ext_vector_type(8))) short short8;
typedef __attribute__((ext_vector_type(4))) float f32x4;

__device__ __forceinline__ void gload_lds16(const void* g, void* l) {
  __builtin_amdgcn_global_load_lds(
      (const __attribute__((address_space(1))) void*)g,
      (__attribute__((address_space(3))) void*)l, 16, 0, 0);
}

// Kernel 1: fp32 -> bf16 + row norms of bf16-rounded values; first 16 blocks
// also zero the (pos,all) atomic accumulators.
__global__ void prep_kernel(const float* __restrict__ x,
                            ushort* __restrict__ xb,
                            float* __restrict__ norms,
                            float* __restrict__ part) {
  if (blockIdx.x < 16)
    ((float4*)part)[blockIdx.x * 256 + threadIdx.x] = make_float4(0.f, 0.f, 0.f, 0.f);
  const int row  = blockIdx.x * 4 + (threadIdx.x >> 6);
  const int lane = threadIdx.x & 63;
  const float4* xr = (const float4*)(x + (size_t)row * DIM);
  ushort4* xbr = (ushort4*)(xb + (size_t)row * DIM);
  float acc = 0.f;
  #pragma unroll
  for (int c = 0; c < DIM / 4 / 64; ++c) {   // 3
    float4 v = xr[c * 64 + lane];
    union { __hip_bfloat16 b; ushort u; } cv;
    ushort4 o;
    cv.b = __float2bfloat16(v.x); o.x = cv.u; float f0 = __bfloat162float(cv.b);
    cv.b = __float2bfloat16(v.y); o.y = cv.u; float f1 = __bfloat162float(cv.b);
    cv.b = __float2bfloat16(v.z); o.z = cv.u; float f2 = __bfloat162float(cv.b);
    cv.b = __float2bfloat16(v.w); o.w = cv.u; float f3 = __bfloat162float(cv.b);
    acc += f0 * f0 + f1 * f1 + f2 * f2 + f3 * f3;
    xbr[c * 64 + lane] = o;
  }
  #pragma unroll
  for (int off = 32; off; off >>= 1) acc += __shfl_down(acc, off);
  if (lane == 0) norms[row] = acc;
}

// Kernel 2: persistent blocks; each handles 1-2 upper-triangle 256x256 tiles.
__global__ __launch_bounds__(512, 2)
void fused_kernel(const ushort* __restrict__ xb,
                  const float* __restrict__ norms,
                  const int* __restrict__ labels,
                  float* __restrict__ part) {  // part[2*row]=pos, [2*row+1]=all
  __shared__ ushort sh[65536];   // 128 KiB: [A/B][dbuf][half][128*64]
  #define SH(ab, p, h) (sh + ((((ab) * 2 + (p)) * 2 + (h)) * 8192))

  const int tid  = threadIdx.x;
  const int lane = tid & 63;
  const int wid  = tid >> 6;        // 0..7
  const int wm   = wid >> 2;        // 0,1  -> rows wm*128..
  const int wn   = wid & 3;         // 0..3 -> cols wn*64..
  const int ln15 = lane & 15, hi4 = lane >> 4;
  const int slotx = ln15 & 7;
  const int brow7 = (wn & 1) * 64;

  // staging geometry (tile-independent): LDS dest linear (wave-uniform base +
  // lane*16B), global source slot XOR'd by row (T2; verified conflict-free).
  const int c0 = tid, c1 = 512 + tid;
  const int r0 = c0 >> 3, r1 = c1 >> 3;
  const size_t gao0 = (size_t)r0 * DIM + ((c0 & 7) ^ (r0 & 7)) * 8;
  const size_t gao1 = (size_t)r1 * DIM + ((c1 & 7) ^ (r1 & 7)) * 8;
  const int d0 = c0 * 8, d1 = c1 * 8;

  // stage half-tile h of A(ab=0)/B(ab=1), K-tile kt, into parity P
  #define STAGEH(ab, h, P, kt) do {                                        \
      const ushort* _g = ((ab) == 0 ? gA : gB) + (size_t)(h) * 128 * DIM + (kt) * BK; \
      ushort* _l = SH(ab, P, h);                                           \
      gload_lds16(_g + gao0, _l + d0);                                     \
      gload_lds16(_g + gao1, _l + d1);                                     \
    } while (0)

  #define READ_A(mibase)                                                   \
    _Pragma("unroll")                                                      \
    for (int mi = 0; mi < 4; ++mi)                                         \
      _Pragma("unroll")                                                    \
      for (int kk = 0; kk < 2; ++kk)                                       \
        aR[mi][kk] = *(const short8*)&Ab[((mibase + mi) * 16 + ln15) * 64 +  \
                                         ((((kk << 2) | hi4) ^ slotx) << 3)];
  #define READ_B(njbase)                                                   \
    _Pragma("unroll")                                                      \
    for (int nq = 0; nq < 2; ++nq)                                         \
      _Pragma("unroll")                                                    \
      for (int kk = 0; kk < 2; ++kk)                                       \
        bR[njbase + nq][kk] = *(const short8*)&Bb[(brow7 + (njbase + nq) * 16 + ln15) * 64 + \
                                                  ((((kk << 2) | hi4) ^ slotx) << 3)];
  #define QUAD(mibase, njbase)                                             \
    __builtin_amdgcn_s_setprio(1);                                         \
    _Pragma("unroll")                                                      \
    for (int mi = 0; mi < 4; ++mi)                                         \
      _Pragma("unroll")                                                    \
      for (int nq = 0; nq < 2; ++nq)                                       \
        _Pragma("unroll")                                                  \
        for (int kk = 0; kk < 2; ++kk)                                     \
          acc[mibase + mi][njbase + nq] = __builtin_amdgcn_mfma_f32_16x16x32_bf16( \
              aR[mi][kk], bR[njbase + nq][kk], acc[mibase + mi][njbase + nq], 0, 0, 0); \
    __builtin_amdgcn_s_setprio(0);

  for (int w = blockIdx.x; w < NTILES; w += GRID) {
    // bijective XCD-chunk swizzle (NTILES % 8 == 0) + triangular decode
    const int t = (w & 7) * (NTILES / 8) + (w >> 3);
    int bi = (int)(((double)(2 * NBLK + 1) -
                    sqrt((double)(2 * NBLK + 1) * (2 * NBLK + 1) - 8.0 * t)) * 0.5);
    while ((bi + 1) * (2 * NBLK - bi) / 2 <= t) ++bi;
    while (bi * (2 * NBLK - bi + 1) / 2 > t) --bi;
    const int bj = bi + (t - bi * (2 * NBLK - bi + 1) / 2);
    const bool diag = (bi == bj);
    const int brow = bi * BM, bcol = bj * BM;
    const ushort* gA = xb + (size_t)brow * DIM;
    const ushort* gB = xb + (size_t)bcol * DIM;

    __syncthreads();   // previous tile's epilogue LDS reads done; full drain

    f32x4 zero = {0.f, 0.f, 0.f, 0.f};
    f32x4 acc[8][4];
    #pragma unroll
    for (int mi = 0; mi < 8; ++mi)
      #pragma unroll
      for (int nj = 0; nj < 4; ++nj) acc[mi][nj] = zero;

    // prologue: kt0 fully; kt1 B0,B1,A0 (A1 staged in ph0 of kt=0)
    STAGEH(0, 0, 0, 0); STAGEH(0, 1, 0, 0); STAGEH(1, 0, 0, 0); STAGEH(1, 1, 0, 0);
    STAGEH(1, 0, 1, 1); STAGEH(1, 1, 1, 1); STAGEH(0, 0, 1, 1);
    asm volatile("s_waitcnt vmcnt(6)");          // kt0 landed; kt1's 6 in flight
    __builtin_amdgcn_sched_barrier(0);
    __builtin_amdgcn_s_barrier();

    for (int kt = 0; kt < NKT; ++kt) {
      const int p = kt & 1;
      const ushort* Ab = SH(0, p, wm);        // wave reads only its A-half
      const ushort* Bb = SH(1, p, wn >> 1);   // and its B-half
      short8 aR[4][2], bR[4][2];

      // ph0: reads A[m0-3]+B[n0-1]; stage A1(kt+1) into other parity
      READ_A(0); READ_B(0);
      if (kt + 1 < NKT) STAGEH(0, 1, p ^ 1, kt + 1);
      __builtin_amdgcn_s_barrier();
      asm volatile("s_waitcnt lgkmcnt(0)");
      __builtin_amdgcn_sched_barrier(0);
      QUAD(0, 0);
      __builtin_amdgcn_s_barrier();

      // ph1: reads B[n2-3] (B region last read here)
      READ_B(2);
      __builtin_amdgcn_s_barrier();
      asm volatile("s_waitcnt lgkmcnt(0)");
      __builtin_amdgcn_sched_barrier(0);
      QUAD(0, 2);
      __builtin_amdgcn_s_barrier();

      // ph2: reads A[m4-7] (A region last read here); stage B0(kt+2)
      READ_A(4);
      if (kt + 2 < NKT) STAGEH(1, 0, p, kt + 2);
      __builtin_amdgcn_s_barrier();
      asm volatile("s_waitcnt lgkmcnt(0)");
      __builtin_amdgcn_sched_barrier(0);
      QUAD(4, 2);
      __builtin_amdgcn_s_barrier();

      // ph3: stage B1(kt+2), A0(kt+2); register-only quad; counted vmcnt
      if (kt + 2 < NKT) { STAGEH(1, 1, p, kt + 2); STAGEH(0, 0, p, kt + 2); }
      __builtin_amdgcn_s_barrier();
      QUAD(4, 0);
      if (kt < NKT - 2) {
        asm volatile("s_waitcnt vmcnt(6)");   // kt+1 complete; kt+2's 6 in flight
      } else {
        asm volatile("s_waitcnt vmcnt(0)");   // tail drain
      }
      __builtin_amdgcn_sched_barrier(0);
      __builtin_amdgcn_s_barrier();
    }

    // ---- epilogue ----
    __syncthreads();                       // LDS now reusable for reductions
    float* redr = (float*)sh;              // [4 wn][256 rows][2]
    float* redc = redr + 4 * 256 * 2;      // [2 wm][256 cols][2]

    float hj2neg[4], fc1[4], fc0[4];
    int lc[4];
    #pragma unroll
    for (int nj = 0; nj < 4; ++nj) {
      int col = bcol + wn * 64 + nj * 16 + ln15;
      hj2neg[nj] = -0.5f * L2E * norms[col];
      lc[nj] = labels[col];
      fc1[nj] = (float)lc[nj]; fc0[nj] = 1.0f - fc1[nj];
    }
    float cs0[4] = {0.f, 0.f, 0.f, 0.f}, cs1[4] = {0.f, 0.f, 0.f, 0.f};

    #pragma unroll
    for (int mi = 0; mi < 8; ++mi) {
      const int rbase = brow + wm * 128 + mi * 16 + hi4 * 4;
      float hi2neg[4], lr1[4];
      #pragma unroll
      for (int r = 0; r < 4; ++r) {
        hi2neg[r] = -0.5f * L2E * norms[rbase + r];
        lr1[r] = (float)labels[rbase + r];
      }
      float hmax = fmaxf(fmaxf(hi2neg[0], hi2neg[1]), fmaxf(hi2neg[2], hi2neg[3]));
      float rs0[4] = {0.f, 0.f, 0.f, 0.f}, rs1[4] = {0.f, 0.f, 0.f, 0.f};
      #pragma unroll
      for (int nj = 0; nj < 4; ++nj) {
        f32x4 a = acc[mi][nj];
        float vmax = fmaxf(fmaxf(a[0], a[1]), fmaxf(a[2], a[3]));
        float tmax = fmaf(vmax, L2E, hmax) + hj2neg[nj];
        if (tmax > -30.f) {   // else all f underflow to 0.0f exactly
          #pragma unroll
          for (int r = 0; r < 4; ++r) {
            float tt = fmaf(a[r], L2E, hi2neg[r]) + hj2neg[nj];
            float f = __builtin_amdgcn_exp2f(tt);
            rs1[r] = fmaf(f, fc1[nj], rs1[r]);       // row-sum, split by COL label
            rs0[r] = fmaf(f, fc0[nj], rs0[r]);
            cs1[nj] = fmaf(f, lr1[r], cs1[nj]);      // col-sum, split by ROW label
            cs0[nj] = fmaf(f, 1.0f - lr1[r], cs0[nj]);
          }
        }
      }
      // reduce rows over the 16 ln15 lanes
      #pragma unroll
      for (int r = 0; r < 4; ++r) {
        float a = rs0[r], b = rs1[r];
        #pragma unroll
        for (int off = 1; off < 16; off <<= 1) {
          a += __shfl_xor(a, off);
          b += __shfl_xor(b, off);
        }
        if (ln15 == 0) {
          int row_l = wm * 128 + mi * 16 + hi4 * 4 + r;
          float pos = (lr1[r] != 0.f) ? b : a;
          redr[(wn * 256 + row_l) * 2 + 0] = pos;
          redr[(wn * 256 + row_l) * 2 + 1] = a + b;
        }
      }
    }

    // reduce cols over the 4 hi4 lane-groups
    #pragma unroll
    for (int nj = 0; nj < 4; ++nj) {
      float a = cs0[nj], b = cs1[nj];
      a += __shfl_xor(a, 16); a += __shfl_xor(a, 32);
      b += __shfl_xor(b, 16); b += __shfl_xor(b, 32);
      if (hi4 == 0) {
        int col_l = wn * 64 + nj * 16 + ln15;
        float pos = lc[nj] ? b : a;
        redc[(wm * 256 + col_l) * 2 + 0] = pos;
        redc[(wm * 256 + col_l) * 2 + 1] = a + b;
      }
    }
    __syncthreads();

    if (tid < 256) {
      float pos = 0.f, all = 0.f;
      #pragma unroll
      for (int ww = 0; ww < 4; ++ww) {
        pos += redr[(ww * 256 + tid) * 2 + 0];
        all += redr[(ww * 256 + tid) * 2 + 1];
      }
      atomicAdd(&part[2 * (brow + tid) + 0], pos);
      atomicAdd(&part[2 * (brow + tid) + 1], all);
      if (!diag) {   // transpose contribution f(j,i) to rows of block bj
        float posc = redc[tid * 2 + 0] + redc[(256 + tid) * 2 + 0];
        float allc = redc[tid * 2 + 1] + redc[(256 + tid) * 2 + 1];
        atomicAdd(&part[2 * (bcol + tid) + 0], posc);
        atomicAdd(&part[2 * (bcol + tid) + 1], allc);
      }
    }
  }
}

// Kernel 3: per-row loss + mean.
__global__ void loss_kernel(const float* __restrict__ part,
                            float* __restrict__ out) {
  int tid = threadIdx.x;  // 1024
  float sum = 0.f;
  for (int row = tid; row < NROWS; row += 1024) {
    float pos = part[2 * row], all = part[2 * row + 1];
    sum += -logf(pos / (all + 1e-8f));
  }
  for (int off = 32; off; off >>= 1) sum += __shfl_down(sum, off);
  __shared__ float w[16];
  if ((tid & 63) == 0) w[tid >> 6] = sum;
  __syncthreads();
  if (tid == 0) {
    float t = 0.f;
    for (int i = 0; i < 16; ++i) t += w[i];
    out[0] = t / (float)NROWS;
  }
}

extern "C" void kernel_launch(void* const* d_in, const int* in_sizes, int n_in,
                              void* d_out, int out_size, void* d_ws, size_t ws_size,
                              hipStream_t stream) {
  const float* x      = (const float*)d_in[0];
  const int*   labels = (const int*)d_in[1];
  char* ws = (char*)d_ws;

  const size_t xb_bytes    = (size_t)NROWS * DIM * 2;   // 12,582,912
  const size_t norms_bytes = (size_t)NROWS * 4;         // 32,768
  const size_t part_bytes  = (size_t)NROWS * 2 * 4;     // 65,536
  if (ws_size < xb_bytes + norms_bytes + part_bytes) return;

  ushort* xb    = (ushort*)ws;
  float*  norms = (float*)(ws + xb_bytes);
  float*  part  = (float*)(ws + xb_bytes + norms_bytes);

  prep_kernel<<<NROWS / 4, 256, 0, stream>>>(x, xb, norms, part);
  fused_kernel<<<GRID, 512, 0, stream>>>(xb, norms, labels, part);
  loss_kernel<<<1, 1024, 0, stream>>>(part, (float*)d_out);
}